// Round 8
// baseline (446.449 us; speedup 1.0000x reference)
//
#include <hip/hip_runtime.h>
#include <hip/hip_bf16.h>

#define NE 1600000
#define NN 100000
#define H 64
#define ED 16
#define NT (NE / 64)        // 25000 edge tiles
#define NB1 391             // ceil(NN/256) scan blocks
#define NNB 1563            // ceil(NN/64) node tiles
#define NSB 6250            // scatter blocks (NE/256)
#define NFB (NSB + NNB)     // fused scatter+y12 grid = 7813

#define KS  72    // bf16 K-stride for K=64 packs (W1ab, W2, sH rows)
#define K3S 136   // bf16 row stride, node GEMM (K=128)
#define YS  68    // fp32 row stride for message rows

typedef __attribute__((ext_vector_type(8))) short short8;
typedef __attribute__((ext_vector_type(4))) float floatx4;

__device__ __forceinline__ unsigned short f2bf(float f) {
    union { float f; unsigned u; } v; v.f = f;
    unsigned r = v.u + 0x7fff + ((v.u >> 16) & 1);
    return (unsigned short)(r >> 16);
}

// v_cvt_pk_bf16_f32: packs 2 f32 -> 2 bf16 (RNE) in ONE VALU op.
__device__ __forceinline__ unsigned cvt_pk_bf16(float lo, float hi) {
    unsigned r;
    asm("v_cvt_pk_bf16_f32 %0, %1, %2" : "=v"(r) : "v"(lo), "v"(hi));
    return r;
}

// silu via fast rcp (1 instr) instead of IEEE divide (~10 instr)
__device__ __forceinline__ float silu(float x) {
    return x * __builtin_amdgcn_rcpf(1.0f + __expf(-x));
}

// ---- prep: x->bf16, weight packs, histogram+rank, agg zero (fused) -----
__global__ void prep_kernel(const float* __restrict__ x,
                            const float* __restrict__ W1,
                            const float* __restrict__ b1,
                            const float* __restrict__ W2,
                            const float* __restrict__ W3,
                            const int* __restrict__ ei,
                            unsigned short* __restrict__ xb,
                            unsigned short* __restrict__ W1abT,
                            unsigned short* __restrict__ W1cT,
                            unsigned short* __restrict__ W2T,
                            unsigned short* __restrict__ W3T,
                            int* __restrict__ cnt,
                            int* __restrict__ rank,
                            float4* __restrict__ aggv) {
    int tid = blockIdx.x * blockDim.x + threadIdx.x;
    int nt = gridDim.x * blockDim.x;
    const float4* xv = (const float4*)x;
    uint2* xbv = (uint2*)xb;
    for (int i = tid; i < NN * H / 4; i += nt) {
        float4 v = xv[i];
        uint2 o;
        o.x = cvt_pk_bf16(v.x, v.y);
        o.y = cvt_pk_bf16(v.z, v.w);
        xbv[i] = o;
    }
    // agg zero (replaces hipMemsetAsync dispatch)
    {
        float4 z = {0.f, 0.f, 0.f, 0.f};
        for (int i = tid; i < NN * H / 4; i += nt) aggv[i] = z;
    }
    // W1abT[n][k]: n<64 -> W1[k][n] (x_src part); n in 64..127 -> W1[64+k][n-64]
    for (int i = tid; i < 128 * KS; i += nt) {
        int n = i / KS, k = i % KS;
        W1abT[i] = (k < 64) ? f2bf(W1[(size_t)((n < 64) ? k : 64 + k) * 64 + (n & 63)])
                            : (unsigned short)0;
    }
    // W1cT[n][k]: k<16 -> W1[128+k][n]; k==16 -> b1[n] (bias slot); else 0
    for (int i = tid; i < 64 * 32; i += nt) {
        int n = i / 32, k = i % 32;
        unsigned short v = 0;
        if (k < 16) v = f2bf(W1[(size_t)(128 + k) * 64 + n]);
        else if (k == 16) v = f2bf(b1[n]);
        W1cT[i] = v;
    }
    for (int i = tid; i < 64 * KS; i += nt) {
        int n = i / KS, k = i % KS;
        W2T[i] = (k < 64) ? f2bf(W2[k * 64 + n]) : (unsigned short)0;
    }
    for (int i = tid; i < 64 * K3S; i += nt) {
        int n = i / K3S, k = i % K3S;
        W3T[i] = (k < 128) ? f2bf(W3[k * 64 + n]) : (unsigned short)0;
    }
    // histogram of dst + per-edge rank (coalesced store)
    for (int e = tid; e < NE; e += nt) {
        rank[e] = atomicAdd(&cnt[ei[NE + e]], 1);
    }
}

// ---- counting-sort scan ------------------------------------------------
__global__ void scan_block_kernel(const int* __restrict__ cnt,
                                  int* __restrict__ offs,
                                  int* __restrict__ bsums) {
    __shared__ int tmp[256];
    int b = blockIdx.x, i = threadIdx.x, idx = b * 256 + i;
    int v = (idx < NN) ? cnt[idx] : 0;
    tmp[i] = v;
    __syncthreads();
    #pragma unroll
    for (int off = 1; off < 256; off <<= 1) {
        int t2 = (i >= off) ? tmp[i - off] : 0;
        __syncthreads();
        tmp[i] += t2;
        __syncthreads();
    }
    if (idx < NN) offs[idx] = tmp[i] - v;
    if (i == 255) bsums[b] = tmp[255];
}

__global__ void scan_sums_kernel(int* __restrict__ bsums) {
    __shared__ int tmp[512];
    int i = threadIdx.x;
    int v = (i < NB1) ? bsums[i] : 0;
    tmp[i] = v;
    __syncthreads();
    #pragma unroll
    for (int off = 1; off < 512; off <<= 1) {
        int t2 = (i >= off) ? tmp[i - off] : 0;
        __syncthreads();
        tmp[i] += t2;
        __syncthreads();
    }
    if (i < NB1) bsums[i] = tmp[i] - v;
}

// ---- fused scatter + y12 -----------------------------------------------
// EMB=1: 64B sorted records [sde 8B | pad 8B | ea-bf16 32B | pad 16B].
// The random write already dirties a full 64B sector for an 8B record, so
// embedding ea is FREE on the write side and converts edge's 102 MB random
// ea gather into a sequential record stream. EMB=0: R7-identical 8B records
// (workspace-size fallback).
template<int EMB>
__global__ __launch_bounds__(256) void scatter_y12_kernel(
    const int* __restrict__ ei,
    const int* __restrict__ offs,
    const int* __restrict__ bsums,
    const int* __restrict__ rank,
    const float* __restrict__ ea,
    char* __restrict__ recs,
    const unsigned short* __restrict__ xb,
    const unsigned short* __restrict__ W1abT,
    unsigned short* __restrict__ yc) {
    __shared__ unsigned short sW[128 * KS];   // 18432 B (y12 role only)
    int bid = blockIdx.x;
    int t = threadIdx.x;

    if (bid % 5 == 0) {
        // ---------------- y12 role: tile = bid/5 ----------------
        {
            const uint4* wv = (const uint4*)W1abT;
            uint4* sv = (uint4*)sW;
            for (int i = t; i < 128 * KS * 2 / 16; i += 256) sv[i] = wv[i];
        }
        __syncthreads();

        int lane = t & 63, w = t >> 6;
        int m = lane & 15, q = lane >> 4;
        int n0 = (bid / 5) * 64;
        int node = n0 + w * 16 + m;           // this lane's node (B-operand col)
        int nclamp = (node < NN) ? node : (NN - 1);

        floatx4 acc[8];
        #pragma unroll
        for (int i = 0; i < 8; i++) acc[i] = (floatx4){0.f, 0.f, 0.f, 0.f};
        #pragma unroll
        for (int kt = 0; kt < 2; kt++) {
            short8 bfr = *(const short8*)(xb + (size_t)nclamp * H + kt * 32 + q * 8);
            #pragma unroll
            for (int tt = 0; tt < 8; tt++) {
                short8 afr = *(const short8*)(sW + (tt * 16 + m) * KS + kt * 32 + q * 8);
                acc[tt] = __builtin_amdgcn_mfma_f32_16x16x32_bf16(afr, bfr, acc[tt], 0, 0, 0);
            }
        }
        if (node < NN) {
            #pragma unroll
            for (int tt = 0; tt < 8; tt++) {
                uint2 o;
                o.x = cvt_pk_bf16(acc[tt][0], acc[tt][1]);
                o.y = cvt_pk_bf16(acc[tt][2], acc[tt][3]);
                *(uint2*)(yc + (size_t)node * 128 + tt * 16 + q * 4) = o;
            }
        }
    } else {
        // ---------------- scatter role ----------------
        int sidx = bid - bid / 5 - 1;         // contiguous [0, 6250)
        int e = sidx * 256 + t;
        int src = ei[e], dst = ei[NE + e];
        int pos = offs[dst] + bsums[dst >> 8] + rank[e];
        unsigned long long sdev = (unsigned long long)src
                                | ((unsigned long long)dst << 17)
                                | ((unsigned long long)e << 34);
        if constexpr (EMB) {
            const float4* p = (const float4*)(ea + (size_t)e * ED);  // coalesced 64B
            float4 v0 = p[0], v1 = p[1], v2 = p[2], v3 = p[3];
            uint4 r1, r2;
            r1.x = cvt_pk_bf16(v0.x, v0.y); r1.y = cvt_pk_bf16(v0.z, v0.w);
            r1.z = cvt_pk_bf16(v1.x, v1.y); r1.w = cvt_pk_bf16(v1.z, v1.w);
            r2.x = cvt_pk_bf16(v2.x, v2.y); r2.y = cvt_pk_bf16(v2.z, v2.w);
            r2.z = cvt_pk_bf16(v3.x, v3.y); r2.w = cvt_pk_bf16(v3.z, v3.w);
            uint4* rec = (uint4*)(recs + ((size_t)pos << 6));
            uint4 r0; r0.x = (unsigned)sdev; r0.y = (unsigned)(sdev >> 32); r0.z = 0; r0.w = 0;
            uint4 rz; rz.x = 0; rz.y = 0; rz.z = 0; rz.w = 0;
            rec[0] = r0; rec[1] = r1; rec[2] = r2; rec[3] = rz;  // full 64B sector
        } else {
            ((unsigned long long*)recs)[pos] = sdev;
        }
    }
}

// ---- edge: h = silu(y1[src]+y2[dst]+ea@W1c+b1); m = silu(h@W2+b2); agg --
// Barrier-free + per-wave LDS slabs (sH/sM aliased, disjoint lifetimes
// within the owning wave; DS ops in-order per wave).
template<int EMB>
__global__ __launch_bounds__(256, 8) void edge_kernel(
    const unsigned short* __restrict__ yc,
    const float* __restrict__ ea,
    const char* __restrict__ recs,
    const unsigned short* __restrict__ W1cT,
    const unsigned short* __restrict__ W2T,
    const float* __restrict__ b2,
    float* __restrict__ agg) {
    __shared__ float sWS[4][1088];            // 4 x 4352 B wave slabs
    __shared__ int sDst[64];

    int t = threadIdx.x;
    int lane = t & 63, w = t >> 6;
    int m = lane & 15, q = lane >> 4;
    int E = w * 16 + m;          // this lane's edge row within the 64-tile

    int src, dst;
    short8 bf1 = {0, 0, 0, 0, 0, 0, 0, 0};
    if constexpr (EMB) {
        const uint4* rec = (const uint4*)(recs + (((size_t)blockIdx.x * 64 + E) << 6));
        uint4 r0 = rec[0];
        unsigned long long sde = ((unsigned long long)r0.y << 32) | r0.x;
        src = (int)(sde & 0x1FFFF);
        dst = (int)((sde >> 17) & 0x1FFFF);
        if (q < 2) {
            union { uint4 u; short8 s; } uv;
            uv.u = rec[1 + q];
            bf1 = uv.s;
        } else if (q == 2) {
            bf1[0] = (short)0x3F80;   // k=16 -> multiplies b1 row
        }
    } else {
        const unsigned long long* sSDE = (const unsigned long long*)recs;
        unsigned long long sde = sSDE[(size_t)blockIdx.x * 64 + E];
        src = (int)(sde & 0x1FFFF);
        dst = (int)((sde >> 17) & 0x1FFFF);
        int e = (int)(sde >> 34);
        if (q < 2) {
            const float4* p = (const float4*)(ea + (size_t)e * ED + q * 8);
            float4 v0 = p[0], v1 = p[1];
            union { unsigned u[4]; short8 s; } ub;
            ub.u[0] = cvt_pk_bf16(v0.x, v0.y);
            ub.u[1] = cvt_pk_bf16(v0.z, v0.w);
            ub.u[2] = cvt_pk_bf16(v1.x, v1.y);
            ub.u[3] = cvt_pk_bf16(v1.z, v1.w);
            bf1 = ub.s;
        } else if (q == 2) {
            bf1[0] = (short)0x3F80;
        }
    }
    if (q == 0) sDst[E] = dst;

    // identity A-fragments (2 distinct; even/odd tt repeat the pattern).
    union uf { unsigned u[4]; short8 s; };
    uf idA, idB;
    {
        unsigned val = (m & 1) ? 0x3F800000u : 0x00003F80u;
        int wsel = (m >> 1) & 3;
        bool gA = (q == (m >> 3));
        bool gB = (q == 2 + (m >> 3));
        #pragma unroll
        for (int i = 0; i < 4; i++) {
            idA.u[i] = (gA && wsel == i) ? val : 0u;
            idB.u[i] = (gB && wsel == i) ? val : 0u;
        }
    }

    // B-fragments: scattered 16B gathers of y1[src], y2[dst] (bf16)
    short8 y1f0 = *(const short8*)(yc + (size_t)src * 128 + q * 8);
    short8 y1f1 = *(const short8*)(yc + (size_t)src * 128 + 32 + q * 8);
    short8 y2f0 = *(const short8*)(yc + (size_t)dst * 128 + 64 + q * 8);
    short8 y2f1 = *(const short8*)(yc + (size_t)dst * 128 + 96 + q * 8);

    // GEMM1: pre = ea@W1c + b1 + y1[src] + y2[dst], all inside MFMA accs
    floatx4 acc[4];
    #pragma unroll
    for (int tt = 0; tt < 4; tt++) {
        short8 w1c = *(const short8*)(W1cT + (tt * 16 + m) * 32 + q * 8);
        floatx4 a = (floatx4){0.f, 0.f, 0.f, 0.f};
        a = __builtin_amdgcn_mfma_f32_16x16x32_bf16(w1c, bf1, a, 0, 0, 0);
        short8 idt = (tt & 1) ? idB.s : idA.s;
        a = __builtin_amdgcn_mfma_f32_16x16x32_bf16(idt, (tt >> 1) ? y1f1 : y1f0, a, 0, 0, 0);
        a = __builtin_amdgcn_mfma_f32_16x16x32_bf16(idt, (tt >> 1) ? y2f1 : y2f0, a, 0, 0, 0);
        acc[tt] = a;
    }

    // epi1: h = silu(pre) -> bf16 -> sH rows in this wave's slab
    unsigned short* sHw = (unsigned short*)sWS[w];
    #pragma unroll
    for (int tt = 0; tt < 4; tt++) {
        uint2 hp;
        hp.x = cvt_pk_bf16(silu(acc[tt][0]), silu(acc[tt][1]));
        hp.y = cvt_pk_bf16(silu(acc[tt][2]), silu(acc[tt][3]));
        *(uint2*)(sHw + m * KS + tt * 16 + q * 4) = hp;
    }

    // GEMM2: C2' = (h@W2)^T ; h fragment as B-operand (intra-wave sH read)
    floatx4 acc2[4];
    #pragma unroll
    for (int i = 0; i < 4; i++) acc2[i] = (floatx4){0.f, 0.f, 0.f, 0.f};
    #pragma unroll
    for (int kt = 0; kt < 2; kt++) {
        short8 hfr = *(const short8*)(sHw + m * KS + kt * 32 + q * 8);
        #pragma unroll
        for (int tt = 0; tt < 4; tt++) {
            short8 w2 = *(const short8*)(W2T + (tt * 16 + m) * KS + kt * 32 + q * 8);
            acc2[tt] = __builtin_amdgcn_mfma_f32_16x16x32_bf16(w2, hfr, acc2[tt], 0, 0, 0);
        }
    }

    // epi2: messages -> sM rows in this wave's slab (aliases sH; safe)
    float* sMw = sWS[w];
    #pragma unroll
    for (int tt = 0; tt < 4; tt++) {
        float4 bb = *(const float4*)(b2 + tt * 16 + q * 4);
        float4 mv;
        mv.x = silu(acc2[tt][0] + bb.x);
        mv.y = silu(acc2[tt][1] + bb.y);
        mv.z = silu(acc2[tt][2] + bb.z);
        mv.w = silu(acc2[tt][3] + bb.w);
        *(float4*)(sMw + m * YS + tt * 16 + q * 4) = mv;
    }

    // segment-reduce: wave w reduces its own 16 rows, lane = column
    {
        int c = lane;
        float s = 0.f;
        int cur = sDst[w * 16];
        #pragma unroll
        for (int r = 0; r < 16; r++) {
            int d = sDst[w * 16 + r];
            if (d != cur) {
                atomicAdd(&agg[(size_t)cur * H + c], s);
                s = 0.f;
                cur = d;
            }
            s += sMw[r * YS + c];
        }
        atomicAdd(&agg[(size_t)cur * H + c], s);
    }
}

// ---- node MLP (transposed MFMA) ----------------------------------------
__global__ __launch_bounds__(256) void node_kernel(
    const unsigned short* __restrict__ xb,
    const float* __restrict__ agg,
    const unsigned short* __restrict__ W3T,
    const float* __restrict__ b3,
    float* __restrict__ out) {
    __shared__ unsigned short sW3[64 * K3S];
    __shared__ unsigned short sA[64 * K3S];

    int t = threadIdx.x;
    int n0 = blockIdx.x * 64;

    {
        const uint4* wv = (const uint4*)W3T;
        uint4* sv = (uint4*)sW3;
        for (int i = t; i < 64 * K3S * 2 / 16; i += 256) sv[i] = wv[i];
    }
    {
        int nL = t >> 2, sub = t & 3;
        int node = n0 + nL;
        uint4* arow = (uint4*)(sA + nL * K3S);
        if (node < NN) {
            const uint4* xs = (const uint4*)(xb + (size_t)node * H);
            arow[sub * 2]     = xs[sub * 2];
            arow[sub * 2 + 1] = xs[sub * 2 + 1];
            const float4* av = (const float4*)(agg + (size_t)node * H);
            unsigned tmp[8];
            #pragma unroll
            for (int j = 0; j < 4; j++) {
                float4 v = av[sub * 4 + j];
                tmp[j * 2 + 0] = cvt_pk_bf16(v.x, v.y);
                tmp[j * 2 + 1] = cvt_pk_bf16(v.z, v.w);
            }
            uint4* drow = (uint4*)(sA + nL * K3S + 64 + sub * 16);
            drow[0] = ((const uint4*)tmp)[0];
            drow[1] = ((const uint4*)tmp)[1];
        } else {
            uint4 z = {0, 0, 0, 0};
            arow[sub * 2] = z; arow[sub * 2 + 1] = z;
            uint4* drow = (uint4*)(sA + nL * K3S + 64 + sub * 16);
            drow[0] = z; drow[1] = z;
        }
    }
    __syncthreads();

    int w = t >> 6, lane = t & 63;
    int m = lane & 15, q = lane >> 4;
    int node = n0 + w * 16 + m;   // this lane's node (B-operand col)

    floatx4 acc[4];
    #pragma unroll
    for (int i = 0; i < 4; i++) acc[i] = (floatx4){0.f, 0.f, 0.f, 0.f};
    #pragma unroll
    for (int kt = 0; kt < 4; kt++) {
        short8 bfr = *(const short8*)(sA + (w * 16 + m) * K3S + kt * 32 + q * 8);
        #pragma unroll
        for (int tt = 0; tt < 4; tt++) {
            short8 afr = *(const short8*)(sW3 + (tt * 16 + m) * K3S + kt * 32 + q * 8);
            acc[tt] = __builtin_amdgcn_mfma_f32_16x16x32_bf16(afr, bfr, acc[tt], 0, 0, 0);
        }
    }
    if (node < NN) {
        #pragma unroll
        for (int tt = 0; tt < 4; tt++) {
            float4 bb = *(const float4*)(b3 + tt * 16 + q * 4);
            float4 ov;
            ov.x = silu(acc[tt][0] + bb.x);
            ov.y = silu(acc[tt][1] + bb.y);
            ov.z = silu(acc[tt][2] + bb.z);
            ov.w = silu(acc[tt][3] + bb.w);
            *(float4*)(out + (size_t)node * H + tt * 16 + q * 4) = ov;
        }
    }
}

static inline size_t align256(size_t x) { return (x + 255) & ~(size_t)255; }

extern "C" void kernel_launch(void* const* d_in, const int* in_sizes, int n_in,
                              void* d_out, int out_size, void* d_ws, size_t ws_size,
                              hipStream_t stream) {
    const float* x  = (const float*)d_in[0];
    const int*   ei = (const int*)d_in[1];
    const float* ea = (const float*)d_in[2];
    const float* W1 = (const float*)d_in[3];
    const float* b1 = (const float*)d_in[4];
    const float* W2 = (const float*)d_in[5];
    const float* b2 = (const float*)d_in[6];
    const float* W3 = (const float*)d_in[7];
    const float* b3 = (const float*)d_in[8];
    float* out = (float*)d_out;

    char* ws = (char*)d_ws;
    size_t o = 0;
    float* agg = (float*)(ws + o);                    o = align256(o + (size_t)NN * H * 4);
    unsigned short* xb = (unsigned short*)(ws + o);   o = align256(o + (size_t)NN * H * 2);
    unsigned short* yc = (unsigned short*)(ws + o);   o = align256(o + (size_t)NN * 128 * 2);
    unsigned short* W1abT = (unsigned short*)(ws + o); o = align256(o + 128 * KS * 2);
    unsigned short* W1cT = (unsigned short*)(ws + o); o = align256(o + 64 * 32 * 2);
    unsigned short* W2T = (unsigned short*)(ws + o);  o = align256(o + 64 * KS * 2);
    unsigned short* W3T = (unsigned short*)(ws + o);  o = align256(o + 64 * K3S * 2);
    int* offs = (int*)(ws + o);                       o = align256(o + (size_t)NN * 4);
    int* bsums = (int*)(ws + o);                      o = align256(o + NB1 * 4);
    int* cnt = (int*)(ws + o);                        o = align256(o + (size_t)NN * 4);
    int* rank = (int*)(ws + o);                       o = align256(o + (size_t)NE * 4);
    char* recs = ws + o;                              // record buffer (size mode-dependent)

    // EMB mode needs NE*64 B of records (~174 MB total); fallback NE*8 (R7 layout).
    bool emb = (ws_size >= o + (size_t)NE * 64);

    hipMemsetAsync(cnt, 0, (size_t)NN * sizeof(int), stream);
    prep_kernel<<<2048, 256, 0, stream>>>(x, W1, b1, W2, W3, ei, xb, W1abT, W1cT, W2T, W3T,
                                          cnt, rank, (float4*)agg);
    scan_block_kernel<<<NB1, 256, 0, stream>>>(cnt, offs, bsums);
    scan_sums_kernel<<<1, 512, 0, stream>>>(bsums);
    if (emb) {
        scatter_y12_kernel<1><<<NFB, 256, 0, stream>>>(ei, offs, bsums, rank, ea, recs,
                                                       xb, W1abT, yc);
        edge_kernel<1><<<NT, 256, 0, stream>>>(yc, ea, recs, W1cT, W2T, b2, agg);
    } else {
        scatter_y12_kernel<0><<<NFB, 256, 0, stream>>>(ei, offs, bsums, rank, ea, recs,
                                                       xb, W1abT, yc);
        edge_kernel<0><<<NT, 256, 0, stream>>>(yc, ea, recs, W1cT, W2T, b2, agg);
    }
    node_kernel<<<NNB, 256, 0, stream>>>(xb, agg, W3T, b3, out);
}

// Round 9
// 424.708 us; speedup vs baseline: 1.0512x; 1.0512x over previous
//
#include <hip/hip_runtime.h>
#include <hip/hip_bf16.h>

#define NE 1600000
#define NN 100000
#define H 64
#define ED 16
#define NT (NE / 64)        // 25000 edge tiles (= 8 x 3125, XCD-divisible)
#define NB1 391             // ceil(NN/256) scan blocks
#define NNB 1563            // ceil(NN/64) node tiles
#define NSB 6250            // scatter blocks (NE/256)
#define NFB (NSB + NNB)     // fused scatter+y12 grid = 7813

#define KS  72    // bf16 K-stride for K=64 packs (W1ab, W2, sH rows)
#define K3S 136   // bf16 row stride, node GEMM (K=128)
#define YS  68    // fp32 row stride for message rows

typedef __attribute__((ext_vector_type(8))) short short8;
typedef __attribute__((ext_vector_type(4))) float floatx4;

__device__ __forceinline__ unsigned short f2bf(float f) {
    union { float f; unsigned u; } v; v.f = f;
    unsigned r = v.u + 0x7fff + ((v.u >> 16) & 1);
    return (unsigned short)(r >> 16);
}

// v_cvt_pk_bf16_f32: packs 2 f32 -> 2 bf16 (RNE) in ONE VALU op.
__device__ __forceinline__ unsigned cvt_pk_bf16(float lo, float hi) {
    unsigned r;
    asm("v_cvt_pk_bf16_f32 %0, %1, %2" : "=v"(r) : "v"(lo), "v"(hi));
    return r;
}

// silu via fast rcp (1 instr) instead of IEEE divide (~10 instr)
__device__ __forceinline__ float silu(float x) {
    return x * __builtin_amdgcn_rcpf(1.0f + __expf(-x));
}

// ---- prep: x->bf16, weight packs, histogram+rank, agg zero (fused) -----
__global__ void prep_kernel(const float* __restrict__ x,
                            const float* __restrict__ W1,
                            const float* __restrict__ b1,
                            const float* __restrict__ W2,
                            const float* __restrict__ W3,
                            const int* __restrict__ ei,
                            unsigned short* __restrict__ xb,
                            unsigned short* __restrict__ W1abT,
                            unsigned short* __restrict__ W1cT,
                            unsigned short* __restrict__ W2T,
                            unsigned short* __restrict__ W3T,
                            int* __restrict__ cnt,
                            int* __restrict__ rank,
                            float4* __restrict__ aggv) {
    int tid = blockIdx.x * blockDim.x + threadIdx.x;
    int nt = gridDim.x * blockDim.x;
    const float4* xv = (const float4*)x;
    uint2* xbv = (uint2*)xb;
    for (int i = tid; i < NN * H / 4; i += nt) {
        float4 v = xv[i];
        uint2 o;
        o.x = cvt_pk_bf16(v.x, v.y);
        o.y = cvt_pk_bf16(v.z, v.w);
        xbv[i] = o;
    }
    // agg zero (replaces hipMemsetAsync dispatch)
    {
        float4 z = {0.f, 0.f, 0.f, 0.f};
        for (int i = tid; i < NN * H / 4; i += nt) aggv[i] = z;
    }
    // W1abT[n][k]: n<64 -> W1[k][n] (x_src part); n in 64..127 -> W1[64+k][n-64]
    for (int i = tid; i < 128 * KS; i += nt) {
        int n = i / KS, k = i % KS;
        W1abT[i] = (k < 64) ? f2bf(W1[(size_t)((n < 64) ? k : 64 + k) * 64 + (n & 63)])
                            : (unsigned short)0;
    }
    // W1cT[n][k]: k<16 -> W1[128+k][n]; k==16 -> b1[n] (bias slot); else 0
    for (int i = tid; i < 64 * 32; i += nt) {
        int n = i / 32, k = i % 32;
        unsigned short v = 0;
        if (k < 16) v = f2bf(W1[(size_t)(128 + k) * 64 + n]);
        else if (k == 16) v = f2bf(b1[n]);
        W1cT[i] = v;
    }
    for (int i = tid; i < 64 * KS; i += nt) {
        int n = i / KS, k = i % KS;
        W2T[i] = (k < 64) ? f2bf(W2[k * 64 + n]) : (unsigned short)0;
    }
    for (int i = tid; i < 64 * K3S; i += nt) {
        int n = i / K3S, k = i % K3S;
        W3T[i] = (k < 128) ? f2bf(W3[k * 64 + n]) : (unsigned short)0;
    }
    // histogram of dst + per-edge rank (coalesced store)
    for (int e = tid; e < NE; e += nt) {
        rank[e] = atomicAdd(&cnt[ei[NE + e]], 1);
    }
}

// ---- counting-sort scan ------------------------------------------------
__global__ void scan_block_kernel(const int* __restrict__ cnt,
                                  int* __restrict__ offs,
                                  int* __restrict__ bsums) {
    __shared__ int tmp[256];
    int b = blockIdx.x, i = threadIdx.x, idx = b * 256 + i;
    int v = (idx < NN) ? cnt[idx] : 0;
    tmp[i] = v;
    __syncthreads();
    #pragma unroll
    for (int off = 1; off < 256; off <<= 1) {
        int t2 = (i >= off) ? tmp[i - off] : 0;
        __syncthreads();
        tmp[i] += t2;
        __syncthreads();
    }
    if (idx < NN) offs[idx] = tmp[i] - v;
    if (i == 255) bsums[b] = tmp[255];
}

__global__ void scan_sums_kernel(int* __restrict__ bsums) {
    __shared__ int tmp[512];
    int i = threadIdx.x;
    int v = (i < NB1) ? bsums[i] : 0;
    tmp[i] = v;
    __syncthreads();
    #pragma unroll
    for (int off = 1; off < 512; off <<= 1) {
        int t2 = (i >= off) ? tmp[i - off] : 0;
        __syncthreads();
        tmp[i] += t2;
        __syncthreads();
    }
    if (i < NB1) bsums[i] = tmp[i] - v;
}

// ---- fused scatter + y12 -----------------------------------------------
// Role split by blockIdx: bid%5==0 -> y12 tile bid/5 (1563 tiles); else
// scatter slice (6250 slices). scan_add folded into the scatter address:
// pos = offs[dst] + bsums[dst>>8] + rank[e]. 8B records (R8 showed the
// 64B ea-embedding record is a net loss: ea in-place is sector-perfect).
__global__ __launch_bounds__(256) void scatter_y12_kernel(
    const int* __restrict__ ei,
    const int* __restrict__ offs,
    const int* __restrict__ bsums,
    const int* __restrict__ rank,
    unsigned long long* __restrict__ sSDE,
    const unsigned short* __restrict__ xb,
    const unsigned short* __restrict__ W1abT,
    unsigned short* __restrict__ yc) {
    __shared__ unsigned short sW[128 * KS];   // 18432 B (y12 role only)
    int bid = blockIdx.x;
    int t = threadIdx.x;

    if (bid % 5 == 0) {
        // ---------------- y12 role: tile = bid/5 ----------------
        {
            const uint4* wv = (const uint4*)W1abT;
            uint4* sv = (uint4*)sW;
            for (int i = t; i < 128 * KS * 2 / 16; i += 256) sv[i] = wv[i];
        }
        __syncthreads();

        int lane = t & 63, w = t >> 6;
        int m = lane & 15, q = lane >> 4;
        int n0 = (bid / 5) * 64;
        int node = n0 + w * 16 + m;           // this lane's node (B-operand col)
        int nclamp = (node < NN) ? node : (NN - 1);

        floatx4 acc[8];
        #pragma unroll
        for (int i = 0; i < 8; i++) acc[i] = (floatx4){0.f, 0.f, 0.f, 0.f};
        #pragma unroll
        for (int kt = 0; kt < 2; kt++) {
            short8 bfr = *(const short8*)(xb + (size_t)nclamp * H + kt * 32 + q * 8);
            #pragma unroll
            for (int tt = 0; tt < 8; tt++) {
                short8 afr = *(const short8*)(sW + (tt * 16 + m) * KS + kt * 32 + q * 8);
                acc[tt] = __builtin_amdgcn_mfma_f32_16x16x32_bf16(afr, bfr, acc[tt], 0, 0, 0);
            }
        }
        if (node < NN) {
            #pragma unroll
            for (int tt = 0; tt < 8; tt++) {
                uint2 o;
                o.x = cvt_pk_bf16(acc[tt][0], acc[tt][1]);
                o.y = cvt_pk_bf16(acc[tt][2], acc[tt][3]);
                *(uint2*)(yc + (size_t)node * 128 + tt * 16 + q * 4) = o;
            }
        }
    } else {
        // ---------------- scatter role ----------------
        int sidx = bid - bid / 5 - 1;         // contiguous [0, 6250)
        int e = sidx * 256 + t;
        int src = ei[e], dst = ei[NE + e];
        int pos = offs[dst] + bsums[dst >> 8] + rank[e];
        unsigned long long v = (unsigned long long)src
                             | ((unsigned long long)dst << 17)
                             | ((unsigned long long)e << 34);
        sSDE[pos] = v;
    }
}

// ---- edge: h = silu(y1[src]+y2[dst]+ea@W1c+b1); m = silu(h@W2+b2); agg --
// Barrier-free + per-wave LDS slabs (sH/sM aliased, disjoint lifetimes
// within the owning wave; DS ops in-order per wave).
// XCD-chunked tile swizzle: records are dst-sorted, so consecutive tiles
// share yc[dst] rows; chunking gives each XCD a contiguous 200K-edge run
// whose y2 working set (~1.6 MB) fits its private 4 MB L2.
__global__ __launch_bounds__(256, 8) void edge_kernel(
    const unsigned short* __restrict__ yc,
    const float* __restrict__ ea,
    const unsigned long long* __restrict__ sSDE,
    const unsigned short* __restrict__ W1cT,
    const unsigned short* __restrict__ W2T,
    const float* __restrict__ b2,
    float* __restrict__ agg) {
    __shared__ float sWS[4][1088];            // 4 x 4352 B wave slabs
    __shared__ int sDst[64];

    int t = threadIdx.x;
    int lane = t & 63, w = t >> 6;
    int m = lane & 15, q = lane >> 4;
    int E = w * 16 + m;          // this lane's edge row within the 64-tile

    // bijective chunked XCD swizzle (NT = 25000 = 8 * 3125 exactly)
    int bid = blockIdx.x;
    int tile = (bid & 7) * (NT / 8) + (bid >> 3);

    unsigned long long sde = sSDE[(size_t)tile * 64 + E];
    int src = (int)(sde & 0x1FFFF);
    int dst = (int)((sde >> 17) & 0x1FFFF);
    int e   = (int)(sde >> 34);
    if (q == 0) sDst[E] = dst;

    // identity A-fragments (2 distinct; even/odd tt repeat the pattern).
    union uf { unsigned u[4]; short8 s; };
    uf idA, idB;
    {
        unsigned val = (m & 1) ? 0x3F800000u : 0x00003F80u;
        int wsel = (m >> 1) & 3;
        bool gA = (q == (m >> 3));
        bool gB = (q == 2 + (m >> 3));
        #pragma unroll
        for (int i = 0; i < 4; i++) {
            idA.u[i] = (gA && wsel == i) ? val : 0u;
            idB.u[i] = (gB && wsel == i) ? val : 0u;
        }
    }

    // B-fragments: scattered 16B gathers of y1[src], y2[dst] (bf16)
    short8 y1f0 = *(const short8*)(yc + (size_t)src * 128 + q * 8);
    short8 y1f1 = *(const short8*)(yc + (size_t)src * 128 + 32 + q * 8);
    short8 y2f0 = *(const short8*)(yc + (size_t)dst * 128 + 64 + q * 8);
    short8 y2f1 = *(const short8*)(yc + (size_t)dst * 128 + 96 + q * 8);

    // GEMM1 B-operand from ea (K=32 with bias slot at k=16)
    short8 bf1 = {0, 0, 0, 0, 0, 0, 0, 0};
    if (q < 2) {
        const float4* p = (const float4*)(ea + (size_t)e * ED + q * 8);
        float4 v0 = p[0], v1 = p[1];
        union { unsigned u[4]; short8 s; } ub;
        ub.u[0] = cvt_pk_bf16(v0.x, v0.y);
        ub.u[1] = cvt_pk_bf16(v0.z, v0.w);
        ub.u[2] = cvt_pk_bf16(v1.x, v1.y);
        ub.u[3] = cvt_pk_bf16(v1.z, v1.w);
        bf1 = ub.s;
    } else if (q == 2) {
        bf1[0] = (short)0x3F80;   // k=16 -> multiplies b1 row
    }

    // GEMM1: pre = ea@W1c + b1 + y1[src] + y2[dst], all inside MFMA accs
    floatx4 acc[4];
    #pragma unroll
    for (int tt = 0; tt < 4; tt++) {
        short8 w1c = *(const short8*)(W1cT + (tt * 16 + m) * 32 + q * 8);
        floatx4 a = (floatx4){0.f, 0.f, 0.f, 0.f};
        a = __builtin_amdgcn_mfma_f32_16x16x32_bf16(w1c, bf1, a, 0, 0, 0);
        short8 idt = (tt & 1) ? idB.s : idA.s;
        a = __builtin_amdgcn_mfma_f32_16x16x32_bf16(idt, (tt >> 1) ? y1f1 : y1f0, a, 0, 0, 0);
        a = __builtin_amdgcn_mfma_f32_16x16x32_bf16(idt, (tt >> 1) ? y2f1 : y2f0, a, 0, 0, 0);
        acc[tt] = a;
    }

    // epi1: h = silu(pre) -> bf16 -> sH rows in this wave's slab
    unsigned short* sHw = (unsigned short*)sWS[w];
    #pragma unroll
    for (int tt = 0; tt < 4; tt++) {
        uint2 hp;
        hp.x = cvt_pk_bf16(silu(acc[tt][0]), silu(acc[tt][1]));
        hp.y = cvt_pk_bf16(silu(acc[tt][2]), silu(acc[tt][3]));
        *(uint2*)(sHw + m * KS + tt * 16 + q * 4) = hp;
    }

    // GEMM2: C2' = (h@W2)^T ; h fragment as B-operand (intra-wave sH read)
    floatx4 acc2[4];
    #pragma unroll
    for (int i = 0; i < 4; i++) acc2[i] = (floatx4){0.f, 0.f, 0.f, 0.f};
    #pragma unroll
    for (int kt = 0; kt < 2; kt++) {
        short8 hfr = *(const short8*)(sHw + m * KS + kt * 32 + q * 8);
        #pragma unroll
        for (int tt = 0; tt < 4; tt++) {
            short8 w2 = *(const short8*)(W2T + (tt * 16 + m) * KS + kt * 32 + q * 8);
            acc2[tt] = __builtin_amdgcn_mfma_f32_16x16x32_bf16(w2, hfr, acc2[tt], 0, 0, 0);
        }
    }

    // epi2: messages -> sM rows in this wave's slab (aliases sH; safe)
    float* sMw = sWS[w];
    #pragma unroll
    for (int tt = 0; tt < 4; tt++) {
        float4 bb = *(const float4*)(b2 + tt * 16 + q * 4);
        float4 mv;
        mv.x = silu(acc2[tt][0] + bb.x);
        mv.y = silu(acc2[tt][1] + bb.y);
        mv.z = silu(acc2[tt][2] + bb.z);
        mv.w = silu(acc2[tt][3] + bb.w);
        *(float4*)(sMw + m * YS + tt * 16 + q * 4) = mv;
    }

    // segment-reduce: wave w reduces its own 16 rows, lane = column
    {
        int c = lane;
        float s = 0.f;
        int cur = sDst[w * 16];
        #pragma unroll
        for (int r = 0; r < 16; r++) {
            int d = sDst[w * 16 + r];
            if (d != cur) {
                atomicAdd(&agg[(size_t)cur * H + c], s);
                s = 0.f;
                cur = d;
            }
            s += sMw[r * YS + c];
        }
        atomicAdd(&agg[(size_t)cur * H + c], s);
    }
}

// ---- node MLP (transposed MFMA) ----------------------------------------
__global__ __launch_bounds__(256) void node_kernel(
    const unsigned short* __restrict__ xb,
    const float* __restrict__ agg,
    const unsigned short* __restrict__ W3T,
    const float* __restrict__ b3,
    float* __restrict__ out) {
    __shared__ unsigned short sW3[64 * K3S];
    __shared__ unsigned short sA[64 * K3S];

    int t = threadIdx.x;
    int n0 = blockIdx.x * 64;

    {
        const uint4* wv = (const uint4*)W3T;
        uint4* sv = (uint4*)sW3;
        for (int i = t; i < 64 * K3S * 2 / 16; i += 256) sv[i] = wv[i];
    }
    {
        int nL = t >> 2, sub = t & 3;
        int node = n0 + nL;
        uint4* arow = (uint4*)(sA + nL * K3S);
        if (node < NN) {
            const uint4* xs = (const uint4*)(xb + (size_t)node * H);
            arow[sub * 2]     = xs[sub * 2];
            arow[sub * 2 + 1] = xs[sub * 2 + 1];
            const float4* av = (const float4*)(agg + (size_t)node * H);
            unsigned tmp[8];
            #pragma unroll
            for (int j = 0; j < 4; j++) {
                float4 v = av[sub * 4 + j];
                tmp[j * 2 + 0] = cvt_pk_bf16(v.x, v.y);
                tmp[j * 2 + 1] = cvt_pk_bf16(v.z, v.w);
            }
            uint4* drow = (uint4*)(sA + nL * K3S + 64 + sub * 16);
            drow[0] = ((const uint4*)tmp)[0];
            drow[1] = ((const uint4*)tmp)[1];
        } else {
            uint4 z = {0, 0, 0, 0};
            arow[sub * 2] = z; arow[sub * 2 + 1] = z;
            uint4* drow = (uint4*)(sA + nL * K3S + 64 + sub * 16);
            drow[0] = z; drow[1] = z;
        }
    }
    __syncthreads();

    int w = t >> 6, lane = t & 63;
    int m = lane & 15, q = lane >> 4;
    int node = n0 + w * 16 + m;   // this lane's node (B-operand col)

    floatx4 acc[4];
    #pragma unroll
    for (int i = 0; i < 4; i++) acc[i] = (floatx4){0.f, 0.f, 0.f, 0.f};
    #pragma unroll
    for (int kt = 0; kt < 4; kt++) {
        short8 bfr = *(const short8*)(sA + (w * 16 + m) * K3S + kt * 32 + q * 8);
        #pragma unroll
        for (int tt = 0; tt < 4; tt++) {
            short8 afr = *(const short8*)(sW3 + (tt * 16 + m) * K3S + kt * 32 + q * 8);
            acc[tt] = __builtin_amdgcn_mfma_f32_16x16x32_bf16(afr, bfr, acc[tt], 0, 0, 0);
        }
    }
    if (node < NN) {
        #pragma unroll
        for (int tt = 0; tt < 4; tt++) {
            float4 bb = *(const float4*)(b3 + tt * 16 + q * 4);
            float4 ov;
            ov.x = silu(acc[tt][0] + bb.x);
            ov.y = silu(acc[tt][1] + bb.y);
            ov.z = silu(acc[tt][2] + bb.z);
            ov.w = silu(acc[tt][3] + bb.w);
            *(float4*)(out + (size_t)node * H + tt * 16 + q * 4) = ov;
        }
    }
}

static inline size_t align256(size_t x) { return (x + 255) & ~(size_t)255; }

extern "C" void kernel_launch(void* const* d_in, const int* in_sizes, int n_in,
                              void* d_out, int out_size, void* d_ws, size_t ws_size,
                              hipStream_t stream) {
    const float* x  = (const float*)d_in[0];
    const int*   ei = (const int*)d_in[1];
    const float* ea = (const float*)d_in[2];
    const float* W1 = (const float*)d_in[3];
    const float* b1 = (const float*)d_in[4];
    const float* W2 = (const float*)d_in[5];
    const float* b2 = (const float*)d_in[6];
    const float* W3 = (const float*)d_in[7];
    const float* b3 = (const float*)d_in[8];
    float* out = (float*)d_out;

    char* ws = (char*)d_ws;
    size_t o = 0;
    float* agg = (float*)(ws + o);                    o = align256(o + (size_t)NN * H * 4);
    unsigned short* xb = (unsigned short*)(ws + o);   o = align256(o + (size_t)NN * H * 2);
    unsigned short* yc = (unsigned short*)(ws + o);   o = align256(o + (size_t)NN * 128 * 2);
    unsigned short* W1abT = (unsigned short*)(ws + o); o = align256(o + 128 * KS * 2);
    unsigned short* W1cT = (unsigned short*)(ws + o); o = align256(o + 64 * 32 * 2);
    unsigned short* W2T = (unsigned short*)(ws + o);  o = align256(o + 64 * KS * 2);
    unsigned short* W3T = (unsigned short*)(ws + o);  o = align256(o + 64 * K3S * 2);
    int* offs = (int*)(ws + o);                       o = align256(o + (size_t)NN * 4);
    int* bsums = (int*)(ws + o);                      o = align256(o + NB1 * 4);
    int* cnt = (int*)(ws + o);                        o = align256(o + (size_t)NN * 4);
    int* rank = (int*)(ws + o);                       o = align256(o + (size_t)NE * 4);
    unsigned long long* sSDE = (unsigned long long*)(ws + o); o = align256(o + (size_t)NE * 8);

    hipMemsetAsync(cnt, 0, (size_t)NN * sizeof(int), stream);
    prep_kernel<<<2048, 256, 0, stream>>>(x, W1, b1, W2, W3, ei, xb, W1abT, W1cT, W2T, W3T,
                                          cnt, rank, (float4*)agg);
    scan_block_kernel<<<NB1, 256, 0, stream>>>(cnt, offs, bsums);
    scan_sums_kernel<<<1, 512, 0, stream>>>(bsums);
    scatter_y12_kernel<<<NFB, 256, 0, stream>>>(ei, offs, bsums, rank, sSDE, xb, W1abT, yc);
    edge_kernel<<<NT, 256, 0, stream>>>(yc, ea, sSDE, W1cT, W2T, b2, agg);
    node_kernel<<<NNB, 256, 0, stream>>>(xb, agg, W3T, b3, out);
}

// Round 10
// 422.478 us; speedup vs baseline: 1.0567x; 1.0053x over previous
//
#include <hip/hip_runtime.h>
#include <hip/hip_bf16.h>

#define NE 1600000
#define NN 100000
#define H 64
#define ED 16
#define NT (NE / 64)        // 25000 edge tiles (= 8 x 3125, XCD-divisible)
#define NB1 391             // ceil(NN/256) scan blocks
#define NNB 1563            // ceil(NN/64) node tiles
#define NSB 6250            // scatter blocks (NE/256)
#define NFB (NSB + NNB)     // fused scatter+y12 grid = 7813

#define KS  72    // bf16 K-stride for K=64 packs (W1ab, W2, sH rows)
#define K3S 136   // bf16 row stride, node GEMM (K=128)
#define YS  68    // fp32 row stride for message rows

typedef __attribute__((ext_vector_type(8))) short short8;
typedef __attribute__((ext_vector_type(4))) float floatx4;

__device__ __forceinline__ unsigned short f2bf(float f) {
    union { float f; unsigned u; } v; v.f = f;
    unsigned r = v.u + 0x7fff + ((v.u >> 16) & 1);
    return (unsigned short)(r >> 16);
}

// v_cvt_pk_bf16_f32: packs 2 f32 -> 2 bf16 (RNE) in ONE VALU op.
__device__ __forceinline__ unsigned cvt_pk_bf16(float lo, float hi) {
    unsigned r;
    asm("v_cvt_pk_bf16_f32 %0, %1, %2" : "=v"(r) : "v"(lo), "v"(hi));
    return r;
}

// silu via fast rcp (1 instr) instead of IEEE divide (~10 instr)
__device__ __forceinline__ float silu(float x) {
    return x * __builtin_amdgcn_rcpf(1.0f + __expf(-x));
}

// ---- prep: x->bf16, weight packs, histogram+rank, agg zero (fused) -----
__global__ void prep_kernel(const float* __restrict__ x,
                            const float* __restrict__ W1,
                            const float* __restrict__ b1,
                            const float* __restrict__ W2,
                            const float* __restrict__ W3,
                            const int* __restrict__ ei,
                            unsigned short* __restrict__ xb,
                            unsigned short* __restrict__ W1abT,
                            unsigned short* __restrict__ W1cT,
                            unsigned short* __restrict__ W2T,
                            unsigned short* __restrict__ W3T,
                            int* __restrict__ cnt,
                            int* __restrict__ rank,
                            float4* __restrict__ aggv) {
    int tid = blockIdx.x * blockDim.x + threadIdx.x;
    int nt = gridDim.x * blockDim.x;
    const float4* xv = (const float4*)x;
    uint2* xbv = (uint2*)xb;
    for (int i = tid; i < NN * H / 4; i += nt) {
        float4 v = xv[i];
        uint2 o;
        o.x = cvt_pk_bf16(v.x, v.y);
        o.y = cvt_pk_bf16(v.z, v.w);
        xbv[i] = o;
    }
    // agg zero (replaces hipMemsetAsync dispatch)
    {
        float4 z = {0.f, 0.f, 0.f, 0.f};
        for (int i = tid; i < NN * H / 4; i += nt) aggv[i] = z;
    }
    // W1abT[n][k]: n<64 -> W1[k][n] (x_src part); n in 64..127 -> W1[64+k][n-64]
    for (int i = tid; i < 128 * KS; i += nt) {
        int n = i / KS, k = i % KS;
        W1abT[i] = (k < 64) ? f2bf(W1[(size_t)((n < 64) ? k : 64 + k) * 64 + (n & 63)])
                            : (unsigned short)0;
    }
    // W1cT[n][k]: k<16 -> W1[128+k][n]; k==16 -> b1[n] (bias slot); else 0
    for (int i = tid; i < 64 * 32; i += nt) {
        int n = i / 32, k = i % 32;
        unsigned short v = 0;
        if (k < 16) v = f2bf(W1[(size_t)(128 + k) * 64 + n]);
        else if (k == 16) v = f2bf(b1[n]);
        W1cT[i] = v;
    }
    for (int i = tid; i < 64 * KS; i += nt) {
        int n = i / KS, k = i % KS;
        W2T[i] = (k < 64) ? f2bf(W2[k * 64 + n]) : (unsigned short)0;
    }
    for (int i = tid; i < 64 * K3S; i += nt) {
        int n = i / K3S, k = i % K3S;
        W3T[i] = (k < 128) ? f2bf(W3[k * 64 + n]) : (unsigned short)0;
    }
    // histogram of dst + per-edge rank (coalesced store)
    for (int e = tid; e < NE; e += nt) {
        rank[e] = atomicAdd(&cnt[ei[NE + e]], 1);
    }
}

// ---- counting-sort scan ------------------------------------------------
__global__ void scan_block_kernel(const int* __restrict__ cnt,
                                  int* __restrict__ offs,
                                  int* __restrict__ bsums) {
    __shared__ int tmp[256];
    int b = blockIdx.x, i = threadIdx.x, idx = b * 256 + i;
    int v = (idx < NN) ? cnt[idx] : 0;
    tmp[i] = v;
    __syncthreads();
    #pragma unroll
    for (int off = 1; off < 256; off <<= 1) {
        int t2 = (i >= off) ? tmp[i - off] : 0;
        __syncthreads();
        tmp[i] += t2;
        __syncthreads();
    }
    if (idx < NN) offs[idx] = tmp[i] - v;
    if (i == 255) bsums[b] = tmp[255];
}

__global__ void scan_sums_kernel(int* __restrict__ bsums) {
    __shared__ int tmp[512];
    int i = threadIdx.x;
    int v = (i < NB1) ? bsums[i] : 0;
    tmp[i] = v;
    __syncthreads();
    #pragma unroll
    for (int off = 1; off < 512; off <<= 1) {
        int t2 = (i >= off) ? tmp[i - off] : 0;
        __syncthreads();
        tmp[i] += t2;
        __syncthreads();
    }
    if (i < NB1) bsums[i] = tmp[i] - v;
}

// ---- fused scatter + y12 -----------------------------------------------
__global__ __launch_bounds__(256) void scatter_y12_kernel(
    const int* __restrict__ ei,
    const int* __restrict__ offs,
    const int* __restrict__ bsums,
    const int* __restrict__ rank,
    unsigned long long* __restrict__ sSDE,
    const unsigned short* __restrict__ xb,
    const unsigned short* __restrict__ W1abT,
    unsigned short* __restrict__ yc) {
    __shared__ unsigned short sW[128 * KS];   // 18432 B (y12 role only)
    int bid = blockIdx.x;
    int t = threadIdx.x;

    if (bid % 5 == 0) {
        // ---------------- y12 role: tile = bid/5 ----------------
        {
            const uint4* wv = (const uint4*)W1abT;
            uint4* sv = (uint4*)sW;
            for (int i = t; i < 128 * KS * 2 / 16; i += 256) sv[i] = wv[i];
        }
        __syncthreads();

        int lane = t & 63, w = t >> 6;
        int m = lane & 15, q = lane >> 4;
        int n0 = (bid / 5) * 64;
        int node = n0 + w * 16 + m;           // this lane's node (B-operand col)
        int nclamp = (node < NN) ? node : (NN - 1);

        floatx4 acc[8];
        #pragma unroll
        for (int i = 0; i < 8; i++) acc[i] = (floatx4){0.f, 0.f, 0.f, 0.f};
        #pragma unroll
        for (int kt = 0; kt < 2; kt++) {
            short8 bfr = *(const short8*)(xb + (size_t)nclamp * H + kt * 32 + q * 8);
            #pragma unroll
            for (int tt = 0; tt < 8; tt++) {
                short8 afr = *(const short8*)(sW + (tt * 16 + m) * KS + kt * 32 + q * 8);
                acc[tt] = __builtin_amdgcn_mfma_f32_16x16x32_bf16(afr, bfr, acc[tt], 0, 0, 0);
            }
        }
        if (node < NN) {
            #pragma unroll
            for (int tt = 0; tt < 8; tt++) {
                uint2 o;
                o.x = cvt_pk_bf16(acc[tt][0], acc[tt][1]);
                o.y = cvt_pk_bf16(acc[tt][2], acc[tt][3]);
                *(uint2*)(yc + (size_t)node * 128 + tt * 16 + q * 4) = o;
            }
        }
    } else {
        // ---------------- scatter role ----------------
        int sidx = bid - bid / 5 - 1;         // contiguous [0, 6250)
        int e = sidx * 256 + t;
        int src = ei[e], dst = ei[NE + e];
        int pos = offs[dst] + bsums[dst >> 8] + rank[e];
        unsigned long long v = (unsigned long long)src
                             | ((unsigned long long)dst << 17)
                             | ((unsigned long long)e << 34);
        sSDE[pos] = v;
    }
}

// ---- edge: h = silu(y1[src]+y2[dst]+ea@W1c+b1); m = silu(h@W2+b2); agg --
// Tile-wide segment reduce: dst runs fully interior to the tile have a
// single writer grid-wide -> plain coalesced store; only the two boundary
// segments need device atomics. Cuts agg atomics ~4x (12.8M -> ~3.2M
// lane-ops). One __syncthreads before the reduce; wave 0 scans all 64
// rows (segment logic is wave-uniform: sDst[r] same across lanes).
__global__ __launch_bounds__(256, 8) void edge_kernel(
    const unsigned short* __restrict__ yc,
    const float* __restrict__ ea,
    const unsigned long long* __restrict__ sSDE,
    const unsigned short* __restrict__ W1cT,
    const unsigned short* __restrict__ W2T,
    const float* __restrict__ b2,
    float* __restrict__ agg) {
    __shared__ float sWS[4][1088];            // 4 x 4352 B wave slabs
    __shared__ int sDst[64];

    int t = threadIdx.x;
    int lane = t & 63, w = t >> 6;
    int m = lane & 15, q = lane >> 4;
    int E = w * 16 + m;          // this lane's edge row within the 64-tile

    // bijective chunked XCD swizzle (NT = 25000 = 8 * 3125 exactly)
    int bid = blockIdx.x;
    int tile = (bid & 7) * (NT / 8) + (bid >> 3);

    unsigned long long sde = sSDE[(size_t)tile * 64 + E];
    int src = (int)(sde & 0x1FFFF);
    int dst = (int)((sde >> 17) & 0x1FFFF);
    int e   = (int)(sde >> 34);
    if (q == 0) sDst[E] = dst;

    // identity A-fragments (2 distinct; even/odd tt repeat the pattern).
    union uf { unsigned u[4]; short8 s; };
    uf idA, idB;
    {
        unsigned val = (m & 1) ? 0x3F800000u : 0x00003F80u;
        int wsel = (m >> 1) & 3;
        bool gA = (q == (m >> 3));
        bool gB = (q == 2 + (m >> 3));
        #pragma unroll
        for (int i = 0; i < 4; i++) {
            idA.u[i] = (gA && wsel == i) ? val : 0u;
            idB.u[i] = (gB && wsel == i) ? val : 0u;
        }
    }

    // B-fragments: scattered 16B gathers of y1[src], y2[dst] (bf16)
    short8 y1f0 = *(const short8*)(yc + (size_t)src * 128 + q * 8);
    short8 y1f1 = *(const short8*)(yc + (size_t)src * 128 + 32 + q * 8);
    short8 y2f0 = *(const short8*)(yc + (size_t)dst * 128 + 64 + q * 8);
    short8 y2f1 = *(const short8*)(yc + (size_t)dst * 128 + 96 + q * 8);

    // GEMM1 B-operand from ea (K=32 with bias slot at k=16)
    short8 bf1 = {0, 0, 0, 0, 0, 0, 0, 0};
    if (q < 2) {
        const float4* p = (const float4*)(ea + (size_t)e * ED + q * 8);
        float4 v0 = p[0], v1 = p[1];
        union { unsigned u[4]; short8 s; } ub;
        ub.u[0] = cvt_pk_bf16(v0.x, v0.y);
        ub.u[1] = cvt_pk_bf16(v0.z, v0.w);
        ub.u[2] = cvt_pk_bf16(v1.x, v1.y);
        ub.u[3] = cvt_pk_bf16(v1.z, v1.w);
        bf1 = ub.s;
    } else if (q == 2) {
        bf1[0] = (short)0x3F80;   // k=16 -> multiplies b1 row
    }

    // GEMM1: pre = ea@W1c + b1 + y1[src] + y2[dst], all inside MFMA accs
    floatx4 acc[4];
    #pragma unroll
    for (int tt = 0; tt < 4; tt++) {
        short8 w1c = *(const short8*)(W1cT + (tt * 16 + m) * 32 + q * 8);
        floatx4 a = (floatx4){0.f, 0.f, 0.f, 0.f};
        a = __builtin_amdgcn_mfma_f32_16x16x32_bf16(w1c, bf1, a, 0, 0, 0);
        short8 idt = (tt & 1) ? idB.s : idA.s;
        a = __builtin_amdgcn_mfma_f32_16x16x32_bf16(idt, (tt >> 1) ? y1f1 : y1f0, a, 0, 0, 0);
        a = __builtin_amdgcn_mfma_f32_16x16x32_bf16(idt, (tt >> 1) ? y2f1 : y2f0, a, 0, 0, 0);
        acc[tt] = a;
    }

    // epi1: h = silu(pre) -> bf16 -> sH rows in this wave's slab
    unsigned short* sHw = (unsigned short*)sWS[w];
    #pragma unroll
    for (int tt = 0; tt < 4; tt++) {
        uint2 hp;
        hp.x = cvt_pk_bf16(silu(acc[tt][0]), silu(acc[tt][1]));
        hp.y = cvt_pk_bf16(silu(acc[tt][2]), silu(acc[tt][3]));
        *(uint2*)(sHw + m * KS + tt * 16 + q * 4) = hp;
    }

    // GEMM2: C2' = (h@W2)^T ; h fragment as B-operand (intra-wave sH read)
    floatx4 acc2[4];
    #pragma unroll
    for (int i = 0; i < 4; i++) acc2[i] = (floatx4){0.f, 0.f, 0.f, 0.f};
    #pragma unroll
    for (int kt = 0; kt < 2; kt++) {
        short8 hfr = *(const short8*)(sHw + m * KS + kt * 32 + q * 8);
        #pragma unroll
        for (int tt = 0; tt < 4; tt++) {
            short8 w2 = *(const short8*)(W2T + (tt * 16 + m) * KS + kt * 32 + q * 8);
            acc2[tt] = __builtin_amdgcn_mfma_f32_16x16x32_bf16(w2, hfr, acc2[tt], 0, 0, 0);
        }
    }

    // epi2: messages -> sM rows in this wave's slab (aliases sH; all sH
    // reads by this wave completed above, DS in-order per wave)
    float* sMw = sWS[w];
    #pragma unroll
    for (int tt = 0; tt < 4; tt++) {
        float4 bb = *(const float4*)(b2 + tt * 16 + q * 4);
        float4 mv;
        mv.x = silu(acc2[tt][0] + bb.x);
        mv.y = silu(acc2[tt][1] + bb.y);
        mv.z = silu(acc2[tt][2] + bb.z);
        mv.w = silu(acc2[tt][3] + bb.w);
        *(float4*)(sMw + m * YS + tt * 16 + q * 4) = mv;
    }

    __syncthreads();   // all slabs + sDst visible to wave 0

    // tile-wide segment reduce: wave 0, lane = column; wave-uniform branches
    if (w == 0) {
        int c = lane;
        float s = 0.f;
        int cur = sDst[0];
        int segStart = 0;
        #pragma unroll 8
        for (int r = 0; r < 64; r++) {
            int d = sDst[r];
            if (d != cur) {
                float* dp = &agg[(size_t)cur * H + c];
                if (segStart == 0) atomicAdd(dp, s);   // boundary: may span tiles
                else *dp = s;                           // interior: single writer
                s = 0.f; cur = d; segStart = r;
            }
            s += sWS[r >> 4][(r & 15) * YS + c];
        }
        atomicAdd(&agg[(size_t)cur * H + c], s);        // last segment: boundary
    }
}

// ---- node MLP (transposed MFMA) ----------------------------------------
__global__ __launch_bounds__(256) void node_kernel(
    const unsigned short* __restrict__ xb,
    const float* __restrict__ agg,
    const unsigned short* __restrict__ W3T,
    const float* __restrict__ b3,
    float* __restrict__ out) {
    __shared__ unsigned short sW3[64 * K3S];
    __shared__ unsigned short sA[64 * K3S];

    int t = threadIdx.x;
    int n0 = blockIdx.x * 64;

    {
        const uint4* wv = (const uint4*)W3T;
        uint4* sv = (uint4*)sW3;
        for (int i = t; i < 64 * K3S * 2 / 16; i += 256) sv[i] = wv[i];
    }
    {
        int nL = t >> 2, sub = t & 3;
        int node = n0 + nL;
        uint4* arow = (uint4*)(sA + nL * K3S);
        if (node < NN) {
            const uint4* xs = (const uint4*)(xb + (size_t)node * H);
            arow[sub * 2]     = xs[sub * 2];
            arow[sub * 2 + 1] = xs[sub * 2 + 1];
            const float4* av = (const float4*)(agg + (size_t)node * H);
            unsigned tmp[8];
            #pragma unroll
            for (int j = 0; j < 4; j++) {
                float4 v = av[sub * 4 + j];
                tmp[j * 2 + 0] = cvt_pk_bf16(v.x, v.y);
                tmp[j * 2 + 1] = cvt_pk_bf16(v.z, v.w);
            }
            uint4* drow = (uint4*)(sA + nL * K3S + 64 + sub * 16);
            drow[0] = ((const uint4*)tmp)[0];
            drow[1] = ((const uint4*)tmp)[1];
        } else {
            uint4 z = {0, 0, 0, 0};
            arow[sub * 2] = z; arow[sub * 2 + 1] = z;
            uint4* drow = (uint4*)(sA + nL * K3S + 64 + sub * 16);
            drow[0] = z; drow[1] = z;
        }
    }
    __syncthreads();

    int w = t >> 6, lane = t & 63;
    int m = lane & 15, q = lane >> 4;
    int node = n0 + w * 16 + m;   // this lane's node (B-operand col)

    floatx4 acc[4];
    #pragma unroll
    for (int i = 0; i < 4; i++) acc[i] = (floatx4){0.f, 0.f, 0.f, 0.f};
    #pragma unroll
    for (int kt = 0; kt < 4; kt++) {
        short8 bfr = *(const short8*)(sA + (w * 16 + m) * K3S + kt * 32 + q * 8);
        #pragma unroll
        for (int tt = 0; tt < 4; tt++) {
            short8 afr = *(const short8*)(sW3 + (tt * 16 + m) * K3S + kt * 32 + q * 8);
            acc[tt] = __builtin_amdgcn_mfma_f32_16x16x32_bf16(afr, bfr, acc[tt], 0, 0, 0);
        }
    }
    if (node < NN) {
        #pragma unroll
        for (int tt = 0; tt < 4; tt++) {
            float4 bb = *(const float4*)(b3 + tt * 16 + q * 4);
            float4 ov;
            ov.x = silu(acc[tt][0] + bb.x);
            ov.y = silu(acc[tt][1] + bb.y);
            ov.z = silu(acc[tt][2] + bb.z);
            ov.w = silu(acc[tt][3] + bb.w);
            *(float4*)(out + (size_t)node * H + tt * 16 + q * 4) = ov;
        }
    }
}

static inline size_t align256(size_t x) { return (x + 255) & ~(size_t)255; }

extern "C" void kernel_launch(void* const* d_in, const int* in_sizes, int n_in,
                              void* d_out, int out_size, void* d_ws, size_t ws_size,
                              hipStream_t stream) {
    const float* x  = (const float*)d_in[0];
    const int*   ei = (const int*)d_in[1];
    const float* ea = (const float*)d_in[2];
    const float* W1 = (const float*)d_in[3];
    const float* b1 = (const float*)d_in[4];
    const float* W2 = (const float*)d_in[5];
    const float* b2 = (const float*)d_in[6];
    const float* W3 = (const float*)d_in[7];
    const float* b3 = (const float*)d_in[8];
    float* out = (float*)d_out;

    char* ws = (char*)d_ws;
    size_t o = 0;
    float* agg = (float*)(ws + o);                    o = align256(o + (size_t)NN * H * 4);
    unsigned short* xb = (unsigned short*)(ws + o);   o = align256(o + (size_t)NN * H * 2);
    unsigned short* yc = (unsigned short*)(ws + o);   o = align256(o + (size_t)NN * 128 * 2);
    unsigned short* W1abT = (unsigned short*)(ws + o); o = align256(o + 128 * KS * 2);
    unsigned short* W1cT = (unsigned short*)(ws + o); o = align256(o + 64 * 32 * 2);
    unsigned short* W2T = (unsigned short*)(ws + o);  o = align256(o + 64 * KS * 2);
    unsigned short* W3T = (unsigned short*)(ws + o);  o = align256(o + 64 * K3S * 2);
    int* offs = (int*)(ws + o);                       o = align256(o + (size_t)NN * 4);
    int* bsums = (int*)(ws + o);                      o = align256(o + NB1 * 4);
    int* cnt = (int*)(ws + o);                        o = align256(o + (size_t)NN * 4);
    int* rank = (int*)(ws + o);                       o = align256(o + (size_t)NE * 4);
    unsigned long long* sSDE = (unsigned long long*)(ws + o); o = align256(o + (size_t)NE * 8);

    hipMemsetAsync(cnt, 0, (size_t)NN * sizeof(int), stream);
    prep_kernel<<<2048, 256, 0, stream>>>(x, W1, b1, W2, W3, ei, xb, W1abT, W1cT, W2T, W3T,
                                          cnt, rank, (float4*)agg);
    scan_block_kernel<<<NB1, 256, 0, stream>>>(cnt, offs, bsums);
    scan_sums_kernel<<<1, 512, 0, stream>>>(bsums);
    scatter_y12_kernel<<<NFB, 256, 0, stream>>>(ei, offs, bsums, rank, sSDE, xb, W1abT, yc);
    edge_kernel<<<NT, 256, 0, stream>>>(yc, ea, sSDE, W1cT, W2T, b2, agg);
    node_kernel<<<NNB, 256, 0, stream>>>(xb, agg, W3T, b3, out);
}